// Round 1
// baseline (145.165 us; speedup 1.0000x reference)
//
#include <hip/hip_runtime.h>

// Problem constants from the reference: x is (N, T, F) fp32.
constexpr int N_ = 64;
constexpr int T_ = 4096;
constexpr int F_ = 64;
constexpr int F4 = F_ / 4;   // 16 float4 per (n,t) row

// Reflect-pad + validity-mask gather.
//   src = rel<0 ? -rel : (rel<L ? rel : 2L-rel-2), clipped to [0, T-1]
//   out[n,t,:] = t < L+p0+p1 ? x[n,src,:] : 0
// Layout: 16 threads (one float4 each) per (n,t) row -> 256B contiguous
// load+store per row; block of 256 covers 16 consecutive t rows.
__global__ __launch_bounds__(256) void pad_variable_kernel(
    const float4* __restrict__ x,
    const int*    __restrict__ lens,
    const int*    __restrict__ pad,   // (2, N) row-major: pad[0][n]=pad[n], pad[1][n]=pad[N_+n]
    float4*       __restrict__ out,
    int Tp)
{
    const int tid  = threadIdx.x;
    const int f4   = tid & (F4 - 1);      // float4 index within F
    const int trow = tid >> 4;            // which of 16 t-rows this block handles
    const int t    = blockIdx.x * 16 + trow;
    const int n    = blockIdx.y;          // wave-uniform -> lens/pad become s_loads
    if (t >= Tp) return;

    const int L  = lens[n];
    const int p0 = pad[n];
    const int p1 = pad[N_ + n];

    const int rel = t - p0;
    int src = (rel < 0) ? -rel : ((rel < L) ? rel : (2 * L - rel - 2));
    src = min(max(src, 0), T_ - 1);

    const bool valid = t < (L + p0 + p1);

    float4 v = make_float4(0.f, 0.f, 0.f, 0.f);
    if (valid) {
        v = x[(size_t)n * T_ * F4 + (size_t)src * F4 + f4];
    }
    out[(size_t)n * Tp * F4 + (size_t)t * F4 + f4] = v;
}

extern "C" void kernel_launch(void* const* d_in, const int* in_sizes, int n_in,
                              void* d_out, int out_size, void* d_ws, size_t ws_size,
                              hipStream_t stream) {
    const float* x    = (const float*)d_in[0];
    const int*   lens = (const int*)d_in[1];
    const int*   pad  = (const int*)d_in[2];
    // d_in[3] is the Tp scalar on device; recover Tp from out_size instead
    // (out has N*Tp*F elements) so no device->host transfer is needed.
    const int Tp = out_size / (N_ * F_);

    dim3 block(256);
    dim3 grid((Tp + 15) / 16, N_);
    hipLaunchKernelGGL(pad_variable_kernel, grid, block, 0, stream,
                       (const float4*)x, lens, pad, (float4*)d_out, Tp);
}